// Round 11
// baseline (687.088 us; speedup 1.0000x reference)
//
#include <hip/hip_runtime.h>
#include <hip/hip_bf16.h>

typedef __attribute__((ext_vector_type(8))) short bf16x8;
typedef __attribute__((ext_vector_type(4))) float f32x4;

#define HID    128
#define KDIM   256   // 2*HID
#define MT     64    // edges per block

__device__ __forceinline__ unsigned short f2bf(float x) {
    unsigned int u = __float_as_uint(x);
    u += 0x7FFFu + ((u >> 16) & 1u);      // round-to-nearest-even
    return (unsigned short)(u >> 16);
}
__device__ __forceinline__ int pack2(float a, float b) {
    return (int)f2bf(a) | ((int)f2bf(b) << 16);
}
__device__ __forceinline__ float lrelu(float x) { return fmaxf(x, 0.2f * x); }

// ---- fp32 -> bf16 conversion: z + W1 + W2 (grid-stride, vec4) ----
__global__ void convert_all_kernel(const float* __restrict__ z,
                                   const float* __restrict__ W1,
                                   const float* __restrict__ W2,
                                   unsigned short* __restrict__ zb,
                                   unsigned short* __restrict__ w1b,
                                   unsigned short* __restrict__ w2b,
                                   int nz4, int nw14, int nw24) {
    int total = nz4 + nw14 + nw24;
    for (int i = blockIdx.x * blockDim.x + threadIdx.x; i < total;
         i += gridDim.x * blockDim.x) {
        const float4* src;
        unsigned short* dst;
        int j;
        if (i < nz4)             { src = (const float4*)z;  dst = zb;  j = i; }
        else if (i < nz4 + nw14) { src = (const float4*)W1; dst = w1b; j = i - nz4; }
        else                     { src = (const float4*)W2; dst = w2b; j = i - nz4 - nw14; }
        float4 v = src[j];
        ushort4 o;
        o.x = f2bf(v.x); o.y = f2bf(v.y); o.z = f2bf(v.z); o.w = f2bf(v.w);
        *(ushort4*)(dst + (size_t)j * 4) = o;
    }
}

// ---- weights-only conversion (fallback when ws too small for z) ----
__global__ void convert_w_kernel(const float* __restrict__ W1,
                                 const float* __restrict__ W2,
                                 unsigned short* __restrict__ w1b,
                                 unsigned short* __restrict__ w2b,
                                 int nw14, int nw24) {
    int i = blockIdx.x * blockDim.x + threadIdx.x;
    if (i >= nw14 + nw24) return;
    const float4* src;
    unsigned short* dst;
    int j;
    if (i < nw14) { src = (const float4*)W1; dst = w1b; j = i; }
    else          { src = (const float4*)W2; dst = w2b; j = i - nw14; }
    float4 v = src[j];
    ushort4 o;
    o.x = f2bf(v.x); o.y = f2bf(v.y); o.z = f2bf(v.z); o.w = f2bf(v.w);
    *(ushort4*)(dst + (size_t)j * 4) = o;
}

// ---- fused gather + 3-layer MLP, 8 waves x (32 edges x 64 cols) ----
// R6 structure (LDS A-tile staging via global_load_lds, XOR swizzle, aliased
// A/h1 buffer, fused in-register layer 3) but per-wave tile HALVED:
// acc[2][4]=32 regs (was 64), 8 waves/block of 512 threads, wave grid =
// 2 edge-rows x 4 col-groups. (512,6): ~85 unified regs/wave, 3 blocks/CU
// = 24 waves/CU = 6/SIMD for latency hiding via TLP (R6 had 3/SIMD at 33%).
// R8 lesson: direct per-lane global gather (no A-LDS) = scattered 64B
// segments + no prefetch room -> 561us. LDS staging is right.
// R4 lesson: reg cap too low spills acc -> WRITE_SIZE explodes (tripwire).
template <bool ZB>
__global__ __launch_bounds__(512, 6)
void disc_kernel(const float* __restrict__ z,
                 const unsigned short* __restrict__ zb,
                 const int* __restrict__ ei,         // int32 per harness contract
                 const unsigned short* __restrict__ w1b,
                 const float* __restrict__ b1,
                 const unsigned short* __restrict__ w2b,
                 const float* __restrict__ b2,
                 const float* __restrict__ W3,
                 const float* __restrict__ b3,
                 float* __restrict__ out, int E) {
    __shared__ __align__(16) unsigned char smem[33792];  // 32KB A/h1 + 1KB partials

    const int tid  = threadIdx.x;
    const int wave = tid >> 6;
    const int lane = tid & 63;
    const int lr   = lane & 15;
    const int lk   = lane >> 4;
    const int e0   = blockIdx.x * MT;
    const float b3s = b3[0];

    // ---- gather: stage A-tile (64 edges x 256 bf16, swizzled) ----
    if constexpr (ZB) {
        // each wave stages 8 rows via 4 x 1KB global_load_lds (lin dest,
        // pre-swizzled source chunk index)
        #pragma unroll
        for (int t = 0; t < 4; ++t) {
            int row = wave * 8 + t * 2 + (lane >> 5);
            int e = e0 + row; if (e >= E) e = E - 1;
            int s = ei[e];
            int d = ei[E + e];
            int c = (lane & 31) ^ (row & 7);     // logical 16B chunk (swizzle bits 0-2)
            int node = (c < 16) ? s : d;
            const unsigned short* g = zb + (size_t)node * HID + (c & 15) * 8;
            __builtin_amdgcn_global_load_lds(
                (const __attribute__((address_space(1))) unsigned int*)g,
                (__attribute__((address_space(3))) unsigned int*)(smem + wave * 4096 + t * 1024),
                16, 0, 0);
        }
    } else {
        // fp32 fallback: 8 threads/edge, register gather + cvt + swizzled write
        int r = tid >> 3, q = tid & 7;
        int e = e0 + r; if (e >= E) e = E - 1;
        int s = ei[e];
        int d = ei[E + e];
        const float4* zs = (const float4*)(z + (size_t)s * HID);
        const float4* zd = (const float4*)(z + (size_t)d * HID);
        const int swz = (r & 7) << 4;
        #pragma unroll
        for (int j = 0; j < 4; ++j) {
            int c = q * 4 + j;
            const float4* src = (c < 16) ? (zs + c * 2) : (zd + (c - 16) * 2);
            float4 v0 = src[0], v1 = src[1];
            int4 o;
            o.x = pack2(v0.x, v0.y);
            o.y = pack2(v0.z, v0.w);
            o.z = pack2(v1.x, v1.y);
            o.w = pack2(v1.z, v1.w);
            *(int4*)(smem + r * 512 + ((c * 16) ^ swz)) = o;
        }
    }
    __syncthreads();

    // ---- layer 1: h1[64 x 256] = A @ W1^T ----
    // wave (wr,wc): edges [wr*32, +32), cols [wc*64, +64)
    const int wr = wave >> 2;
    const int wc = wave & 3;
    const int m0 = wr * 32;
    const int n0 = wc * 64;

    f32x4 acc[2][4];
    #pragma unroll
    for (int mi = 0; mi < 2; ++mi)
        #pragma unroll
        for (int ni = 0; ni < 4; ++ni)
            acc[mi][ni] = (f32x4){0.f, 0.f, 0.f, 0.f};

    const unsigned short* wb = w1b + (size_t)(n0 + lr) * KDIM + lk * 8;

    #pragma unroll
    for (int ks = 0; ks < 8; ++ks) {
        const int kb = ks * 64 + lk * 16;
        bf16x8 a[2], b[4];
        #pragma unroll
        for (int ni = 0; ni < 4; ++ni)
            b[ni] = *(const bf16x8*)(wb + (size_t)ni * 16 * KDIM + ks * 32);
        #pragma unroll
        for (int mi = 0; mi < 2; ++mi) {
            int row = m0 + mi * 16 + lr;
            a[mi] = *(const bf16x8*)(smem + row * 512 + (kb ^ ((row & 7) << 4)));
        }
        #pragma unroll
        for (int mi = 0; mi < 2; ++mi)
            #pragma unroll
            for (int ni = 0; ni < 4; ++ni)
                acc[mi][ni] = __builtin_amdgcn_mfma_f32_16x16x32_bf16(
                    b[ni], a[mi], acc[mi][ni], 0, 0, 0);   // reg-dim = W1 col
    }
    __syncthreads();   // all waves done reading A -> safe to overwrite with h1

    // epilogue: bias + leaky -> h1 bf16 (packed 4 cols = 8B per write, swizzled)
    #pragma unroll
    for (int ni = 0; ni < 4; ++ni) {
        int colb = n0 + ni * 16 + lk * 4;     // 4 consecutive W1 cols
        float4 bias = *(const float4*)(b1 + colb);
        #pragma unroll
        for (int mi = 0; mi < 2; ++mi) {
            int row = m0 + mi * 16 + lr;
            float x0 = lrelu(acc[mi][ni][0] + bias.x);
            float x1 = lrelu(acc[mi][ni][1] + bias.y);
            float x2 = lrelu(acc[mi][ni][2] + bias.z);
            float x3 = lrelu(acc[mi][ni][3] + bias.w);
            int2 o;
            o.x = pack2(x0, x1);
            o.y = pack2(x2, x3);
            *(int2*)(smem + row * 512 + ((colb * 2) ^ ((row & 7) << 4))) = o;
        }
    }
    __syncthreads();

    // ---- layer 2: [64 x 64] = h1 @ W2^T ----
    // wave: col-group (wave&3)*16, edge half (wave>>2)*32
    f32x4 acc2[2];
    acc2[0] = (f32x4){0.f, 0.f, 0.f, 0.f};
    acc2[1] = (f32x4){0.f, 0.f, 0.f, 0.f};
    const int c2 = wc * 16 + lr;
    const unsigned short* w2base = w2b + (size_t)c2 * KDIM + lk * 8;
    #pragma unroll
    for (int ks = 0; ks < 8; ++ks) {
        const int kb = ks * 64 + lk * 16;
        bf16x8 a2[2];
        #pragma unroll
        for (int mi = 0; mi < 2; ++mi) {
            int row = m0 + mi * 16 + lr;
            a2[mi] = *(const bf16x8*)(smem + row * 512 + (kb ^ ((row & 7) << 4)));
        }
        bf16x8 bw = *(const bf16x8*)(w2base + ks * 32);
        #pragma unroll
        for (int mi = 0; mi < 2; ++mi)
            acc2[mi] = __builtin_amdgcn_mfma_f32_16x16x32_bf16(
                bw, a2[mi], acc2[mi], 0, 0, 0);  // reg-dim = W2 col
    }
    __syncthreads();   // h1 reads done -> safe to overwrite with partials

    // ---- layer 3 fused in registers: partial = sum_c lrelu(h2)*W3[c] ----
    float* part = (float*)(smem + 32768);      // [4 col-groups][64 edges]
    {
        int colb = wc * 16 + lk * 4;
        float4 b2v = *(const float4*)(b2 + colb);
        float4 w3v = *(const float4*)(W3 + colb);
        #pragma unroll
        for (int mi = 0; mi < 2; ++mi) {
            float s = lrelu(acc2[mi][0] + b2v.x) * w3v.x
                    + lrelu(acc2[mi][1] + b2v.y) * w3v.y
                    + lrelu(acc2[mi][2] + b2v.z) * w3v.z
                    + lrelu(acc2[mi][3] + b2v.w) * w3v.w;
            s += __shfl_xor(s, 16);
            s += __shfl_xor(s, 32);
            if (lk == 0) part[wc * 64 + m0 + mi * 16 + lr] = s;
        }
    }
    __syncthreads();

    if (tid < MT) {
        int e = e0 + tid;
        float s = part[tid] + part[64 + tid] + part[128 + tid] + part[192 + tid] + b3s;
        if (e < E) out[e] = s;
    }
}

extern "C" void kernel_launch(void* const* d_in, const int* in_sizes, int n_in,
                              void* d_out, int out_size, void* d_ws, size_t ws_size,
                              hipStream_t stream) {
    const float* z  = (const float*)d_in[0];
    const int*   ei = (const int*)d_in[1];
    const float* W1 = (const float*)d_in[2];
    const float* b1 = (const float*)d_in[3];
    const float* W2 = (const float*)d_in[4];
    const float* b2 = (const float*)d_in[5];
    const float* W3 = (const float*)d_in[6];
    const float* b3 = (const float*)d_in[7];
    float* out = (float*)d_out;

    const int nz  = in_sizes[0];       // 12,800,000
    const int E   = in_sizes[1] / 2;   // 1,000,000
    const int nw1 = in_sizes[2];       // 65,536
    const int nw2 = in_sizes[4];       // 16,384

    const size_t need_full = (size_t)(nz + nw1 + nw2) * 2;
    const bool zb_ok = ws_size >= need_full;

    const int blocks = (E + MT - 1) / MT;   // 15625

    if (zb_ok) {
        unsigned short* zbp = (unsigned short*)d_ws;
        unsigned short* w1b = zbp + nz;
        unsigned short* w2b = w1b + nw1;
        convert_all_kernel<<<2048, 256, 0, stream>>>(z, W1, W2, zbp, w1b, w2b,
                                                     nz / 4, nw1 / 4, nw2 / 4);
        disc_kernel<true><<<blocks, 512, 0, stream>>>(z, zbp, ei, w1b, b1, w2b,
                                                      b2, W3, b3, out, E);
    } else {
        unsigned short* w1b = (unsigned short*)d_ws;
        unsigned short* w2b = w1b + nw1;
        const int ntot = (nw1 + nw2) / 4;
        convert_w_kernel<<<(ntot + 255) / 256, 256, 0, stream>>>(W1, W2, w1b, w2b,
                                                                 nw1 / 4, nw2 / 4);
        disc_kernel<false><<<blocks, 512, 0, stream>>>(z, (const unsigned short*)nullptr,
                                                       ei, w1b, b1, w2b, b2, W3, b3,
                                                       out, E);
    }
}

// Round 12
// 408.548 us; speedup vs baseline: 1.6818x; 1.6818x over previous
//
#include <hip/hip_runtime.h>
#include <hip/hip_bf16.h>

typedef __attribute__((ext_vector_type(8))) short bf16x8;
typedef __attribute__((ext_vector_type(4))) float f32x4;

#define HID    128
#define KDIM   256   // 2*HID
#define MT     64    // edges per block

__device__ __forceinline__ unsigned short f2bf(float x) {
    unsigned int u = __float_as_uint(x);
    u += 0x7FFFu + ((u >> 16) & 1u);      // round-to-nearest-even
    return (unsigned short)(u >> 16);
}
__device__ __forceinline__ int pack2(float a, float b) {
    return (int)f2bf(a) | ((int)f2bf(b) << 16);
}
__device__ __forceinline__ float lrelu(float x) { return fmaxf(x, 0.2f * x); }

// ---- fp32 -> bf16 conversion: z + W1 + W2 (grid-stride, vec4) ----
__global__ void convert_all_kernel(const float* __restrict__ z,
                                   const float* __restrict__ W1,
                                   const float* __restrict__ W2,
                                   unsigned short* __restrict__ zb,
                                   unsigned short* __restrict__ w1b,
                                   unsigned short* __restrict__ w2b,
                                   int nz4, int nw14, int nw24) {
    int total = nz4 + nw14 + nw24;
    for (int i = blockIdx.x * blockDim.x + threadIdx.x; i < total;
         i += gridDim.x * blockDim.x) {
        const float4* src;
        unsigned short* dst;
        int j;
        if (i < nz4)             { src = (const float4*)z;  dst = zb;  j = i; }
        else if (i < nz4 + nw14) { src = (const float4*)W1; dst = w1b; j = i - nz4; }
        else                     { src = (const float4*)W2; dst = w2b; j = i - nz4 - nw14; }
        float4 v = src[j];
        ushort4 o;
        o.x = f2bf(v.x); o.y = f2bf(v.y); o.z = f2bf(v.z); o.w = f2bf(v.w);
        *(ushort4*)(dst + (size_t)j * 4) = o;
    }
}

// ---- weights-only conversion (fallback when ws too small for z) ----
__global__ void convert_w_kernel(const float* __restrict__ W1,
                                 const float* __restrict__ W2,
                                 unsigned short* __restrict__ w1b,
                                 unsigned short* __restrict__ w2b,
                                 int nw14, int nw24) {
    int i = blockIdx.x * blockDim.x + threadIdx.x;
    if (i >= nw14 + nw24) return;
    const float4* src;
    unsigned short* dst;
    int j;
    if (i < nw14) { src = (const float4*)W1; dst = w1b; j = i; }
    else          { src = (const float4*)W2; dst = w2b; j = i - nw14; }
    float4 v = src[j];
    ushort4 o;
    o.x = f2bf(v.x); o.y = f2bf(v.y); o.z = f2bf(v.z); o.w = f2bf(v.w);
    *(ushort4*)(dst + (size_t)j * 4) = o;
}

// ---- fused gather + 3-layer MLP (R6 structure, 4 blocks/CU) ----
// 4 waves x (64 edges x 64 cols) full tiles; one 32 KB LDS buffer phase-
// aliased A-tile -> h1 -> partials; XOR swizzle byte^((row&7)<<4);
// W1/W2 fragment double-buffer prefetch across K-steps.
// History: (256,3)+prefetch = 356us @ VGPR=68 -> fits (256,4) cap of 128,
// so raise residency to 4 blocks/CU (16 waves/CU). (256,5) spills (R4).
// R11 lesson: halved per-wave tiles @ 8 waves = overhead dilution, 634us.
// R8 lesson: direct per-lane global gather (no A-LDS) = 561us.
template <bool ZB>
__global__ __launch_bounds__(256, 4)
void disc_kernel(const float* __restrict__ z,
                 const unsigned short* __restrict__ zb,
                 const int* __restrict__ ei,         // int32 per harness contract
                 const unsigned short* __restrict__ w1b,
                 const float* __restrict__ b1,
                 const unsigned short* __restrict__ w2b,
                 const float* __restrict__ b2,
                 const float* __restrict__ W3,
                 const float* __restrict__ b3,
                 float* __restrict__ out, int E) {
    __shared__ __align__(16) unsigned char smem[32768];

    const int tid  = threadIdx.x;
    const int wave = tid >> 6;
    const int lane = tid & 63;
    const int lr   = lane & 15;
    const int lk   = lane >> 4;
    const int e0   = blockIdx.x * MT;
    const float b3s = b3[0];            // uniform, early s_load

    // ---- gather: stage A-tile (64 edges x 256 bf16, swizzled) ----
    if constexpr (ZB) {
        #pragma unroll
        for (int t = 0; t < 8; ++t) {
            int row = wave * 16 + t * 2 + (lane >> 5);
            int e = e0 + row; if (e >= E) e = E - 1;
            int s = ei[e];
            int d = ei[E + e];
            int c = (lane & 31) ^ (row & 7);     // logical 16B chunk (swizzle bits 0-2)
            int node = (c < 16) ? s : d;
            const unsigned short* g = zb + (size_t)node * HID + (c & 15) * 8;
            __builtin_amdgcn_global_load_lds(
                (const __attribute__((address_space(1))) unsigned int*)g,
                (__attribute__((address_space(3))) unsigned int*)(smem + wave * 8192 + t * 1024),
                16, 0, 0);
        }
    } else {
        int r = tid >> 2, q = tid & 3;
        int e = e0 + r; if (e >= E) e = E - 1;
        int s = ei[e];
        int d = ei[E + e];
        const float4* zs = (const float4*)(z + (size_t)s * HID);
        const float4* zd = (const float4*)(z + (size_t)d * HID);
        const int swz = (r & 7) << 4;
        #pragma unroll
        for (int j = 0; j < 8; ++j) {
            int c = q * 8 + j;
            const float4* src = (c < 16) ? (zs + c * 2) : (zd + (c - 16) * 2);
            float4 v0 = src[0], v1 = src[1];
            int4 o;
            o.x = pack2(v0.x, v0.y);
            o.y = pack2(v0.z, v0.w);
            o.z = pack2(v1.x, v1.y);
            o.w = pack2(v1.z, v1.w);
            *(int4*)(smem + r * 512 + ((c * 16) ^ swz)) = o;
        }
    }

    // ---- issue first W1 fragments BEFORE the barrier (independent of LDS;
    //      they complete during the vmcnt drain) ----
    const int n0 = wave * 64;
    const unsigned short* wbase = w1b + (size_t)(n0 + lr) * KDIM + lk * 8;
    bf16x8 bcur[4], bnxt[4];
    #pragma unroll
    for (int ni = 0; ni < 4; ++ni)
        bcur[ni] = *(const bf16x8*)(wbase + (size_t)ni * 16 * KDIM);

    __syncthreads();

    // ---- layer 1: h1[64 x 256] = A @ W1^T, wave owns 64 W1-cols ----
    // Software-pipelined: weight frags for ks+1 load while ks's MFMAs run.
    f32x4 acc[4][4];
    #pragma unroll
    for (int mi = 0; mi < 4; ++mi)
        #pragma unroll
        for (int ni = 0; ni < 4; ++ni)
            acc[mi][ni] = (f32x4){0.f, 0.f, 0.f, 0.f};

    #pragma unroll
    for (int ks = 0; ks < 8; ++ks) {
        if (ks < 7) {
            #pragma unroll
            for (int ni = 0; ni < 4; ++ni)
                bnxt[ni] = *(const bf16x8*)(wbase + (size_t)ni * 16 * KDIM + (ks + 1) * 32);
        }
        const int kb = ks * 64 + lk * 16;
        bf16x8 a[4];
        #pragma unroll
        for (int mi = 0; mi < 4; ++mi) {
            int row = mi * 16 + lr;
            a[mi] = *(const bf16x8*)(smem + row * 512 + (kb ^ ((row & 7) << 4)));
        }
        #pragma unroll
        for (int mi = 0; mi < 4; ++mi)
            #pragma unroll
            for (int ni = 0; ni < 4; ++ni)
                acc[mi][ni] = __builtin_amdgcn_mfma_f32_16x16x32_bf16(
                    bcur[ni], a[mi], acc[mi][ni], 0, 0, 0);   // reg-dim = W1 col
        if (ks < 7) {
            #pragma unroll
            for (int ni = 0; ni < 4; ++ni) bcur[ni] = bnxt[ni];
        }
    }

    // hoist first W2 fragment above the epilogue (hides under epilogue+barrier)
    const int c2 = wave * 16 + lr;
    const unsigned short* w2base = w2b + (size_t)c2 * KDIM + lk * 8;
    bf16x8 bwc = *(const bf16x8*)(w2base);

    __syncthreads();   // all waves done reading A -> safe to overwrite with h1

    // epilogue: bias + leaky -> h1 bf16 (packed 4 cols = 8B per write)
    #pragma unroll
    for (int ni = 0; ni < 4; ++ni) {
        int colb = n0 + ni * 16 + lk * 4;     // 4 consecutive W1 cols
        float4 bias = *(const float4*)(b1 + colb);
        #pragma unroll
        for (int mi = 0; mi < 4; ++mi) {
            int row = mi * 16 + lr;
            float x0 = lrelu(acc[mi][ni][0] + bias.x);
            float x1 = lrelu(acc[mi][ni][1] + bias.y);
            float x2 = lrelu(acc[mi][ni][2] + bias.z);
            float x3 = lrelu(acc[mi][ni][3] + bias.w);
            int2 o;
            o.x = pack2(x0, x1);
            o.y = pack2(x2, x3);
            *(int2*)(smem + row * 512 + ((colb * 2) ^ ((row & 7) << 4))) = o;
        }
    }
    __syncthreads();

    // ---- layer 2: [64 x 64] = h1 @ W2^T, wave owns 16 W2-cols (pipelined) ----
    f32x4 acc2[4];
    #pragma unroll
    for (int mi = 0; mi < 4; ++mi) acc2[mi] = (f32x4){0.f, 0.f, 0.f, 0.f};
    bf16x8 bwn;
    #pragma unroll
    for (int ks = 0; ks < 8; ++ks) {
        if (ks < 7) bwn = *(const bf16x8*)(w2base + (ks + 1) * 32);
        const int kb = ks * 64 + lk * 16;
        bf16x8 a2[4];
        #pragma unroll
        for (int mi = 0; mi < 4; ++mi) {
            int row = mi * 16 + lr;
            a2[mi] = *(const bf16x8*)(smem + row * 512 + (kb ^ ((row & 7) << 4)));
        }
        #pragma unroll
        for (int mi = 0; mi < 4; ++mi)
            acc2[mi] = __builtin_amdgcn_mfma_f32_16x16x32_bf16(
                bwc, a2[mi], acc2[mi], 0, 0, 0);  // reg-dim = W2 col
        if (ks < 7) bwc = bwn;
    }
    __syncthreads();   // h1 reads done -> safe to overwrite with partials

    // ---- layer 3 fused in registers: partial = sum_c lrelu(h2)*W3[c] ----
    float* part = (float*)smem;                // [4 waves][64 edges]
    {
        int colb = wave * 16 + lk * 4;
        float4 b2v = *(const float4*)(b2 + colb);
        float4 w3v = *(const float4*)(W3 + colb);
        #pragma unroll
        for (int mi = 0; mi < 4; ++mi) {
            float s = lrelu(acc2[mi][0] + b2v.x) * w3v.x
                    + lrelu(acc2[mi][1] + b2v.y) * w3v.y
                    + lrelu(acc2[mi][2] + b2v.z) * w3v.z
                    + lrelu(acc2[mi][3] + b2v.w) * w3v.w;
            s += __shfl_xor(s, 16);
            s += __shfl_xor(s, 32);
            if (lk == 0) part[wave * 64 + mi * 16 + lr] = s;
        }
    }
    __syncthreads();

    if (tid < MT) {
        int e = e0 + tid;
        float s = part[tid] + part[64 + tid] + part[128 + tid] + part[192 + tid] + b3s;
        if (e < E) out[e] = s;
    }
}

extern "C" void kernel_launch(void* const* d_in, const int* in_sizes, int n_in,
                              void* d_out, int out_size, void* d_ws, size_t ws_size,
                              hipStream_t stream) {
    const float* z  = (const float*)d_in[0];
    const int*   ei = (const int*)d_in[1];
    const float* W1 = (const float*)d_in[2];
    const float* b1 = (const float*)d_in[3];
    const float* W2 = (const float*)d_in[4];
    const float* b2 = (const float*)d_in[5];
    const float* W3 = (const float*)d_in[6];
    const float* b3 = (const float*)d_in[7];
    float* out = (float*)d_out;

    const int nz  = in_sizes[0];       // 12,800,000
    const int E   = in_sizes[1] / 2;   // 1,000,000
    const int nw1 = in_sizes[2];       // 65,536
    const int nw2 = in_sizes[4];       // 16,384

    const size_t need_full = (size_t)(nz + nw1 + nw2) * 2;
    const bool zb_ok = ws_size >= need_full;

    const int blocks = (E + MT - 1) / MT;   // 15625

    if (zb_ok) {
        unsigned short* zbp = (unsigned short*)d_ws;
        unsigned short* w1b = zbp + nz;
        unsigned short* w2b = w1b + nw1;
        convert_all_kernel<<<2048, 256, 0, stream>>>(z, W1, W2, zbp, w1b, w2b,
                                                     nz / 4, nw1 / 4, nw2 / 4);
        disc_kernel<true><<<blocks, 256, 0, stream>>>(z, zbp, ei, w1b, b1, w2b,
                                                      b2, W3, b3, out, E);
    } else {
        unsigned short* w1b = (unsigned short*)d_ws;
        unsigned short* w2b = w1b + nw1;
        const int ntot = (nw1 + nw2) / 4;
        convert_w_kernel<<<(ntot + 255) / 256, 256, 0, stream>>>(W1, W2, w1b, w2b,
                                                                 nw1 / 4, nw2 / 4);
        disc_kernel<false><<<blocks, 256, 0, stream>>>(z, (const unsigned short*)nullptr,
                                                       ei, w1b, b1, w2b, b2, W3, b3,
                                                       out, E);
    }
}